// Round 2
// baseline (52.346 us; speedup 1.0000x reference)
//
#include <hip/hip_runtime.h>
#include <hip/hip_bf16.h>

// Problem constants (fixed by the reference file)
constexpr int B_   = 8;
constexpr int C_   = 3;
constexpr int HW_  = 1024 * 1024;         // H*W = 2^20
constexpr int NPIX = B_ * HW_;            // 8,388,608 pixels = 2^23
constexpr int PPT  = 16;                  // pixels per thread
constexpr int NTHREADS = NPIX / PPT;      // 524,288
constexpr int BLOCK = 256;
constexpr int GRID  = NTHREADS / BLOCK;   // 2048

// ln(1e-8)
#define LOGMIN (-18.420680743952367f)
// 1/(B*H*W) = 2^-23 (exact in fp32)
#define INV_DENOM (1.1920928955078125e-07f)

__global__ void zero_out_kernel(float* out) {
    if (threadIdx.x == 0) out[0] = 0.0f;
}

__global__ __launch_bounds__(BLOCK) void ce_fused_kernel(
    const float* __restrict__ x,        // [B][C][H][W]
    const int*   __restrict__ y,        // [B][H][W]
    const float* __restrict__ weight,   // [C]
    const float* __restrict__ mask,     // [B][H][W]
    float* __restrict__ out)
{
    const float w0 = weight[0];
    const float w1 = weight[1];
    const float w2 = weight[2];

    const int tid = blockIdx.x * BLOCK + threadIdx.x;   // < 2^19
    const int p   = tid * PPT;                          // pixel index < 2^23
    const int b   = p >> 20;                            // image index
    const int s   = p & (HW_ - 1);                      // offset within image

    const float* xb = x + (size_t)b * (size_t)(C_ * HW_) + (size_t)s;

    // ---- load phase: 20 independent 16B loads, all issued before any use ----
    float a0[PPT], a1[PPT], a2[PPT], mm[PPT];
    int   yy[PPT];

    #pragma unroll
    for (int k = 0; k < PPT / 4; ++k) {
        const float4 v0 = *reinterpret_cast<const float4*>(xb + k * 4);
        const float4 v1 = *reinterpret_cast<const float4*>(xb + HW_ + k * 4);
        const float4 v2 = *reinterpret_cast<const float4*>(xb + 2 * HW_ + k * 4);
        const int4   yv = *reinterpret_cast<const int4*>(y + p + k * 4);
        const float4 mv = *reinterpret_cast<const float4*>(mask + p + k * 4);
        a0[k*4+0] = v0.x; a0[k*4+1] = v0.y; a0[k*4+2] = v0.z; a0[k*4+3] = v0.w;
        a1[k*4+0] = v1.x; a1[k*4+1] = v1.y; a1[k*4+2] = v1.z; a1[k*4+3] = v1.w;
        a2[k*4+0] = v2.x; a2[k*4+1] = v2.y; a2[k*4+2] = v2.z; a2[k*4+3] = v2.w;
        yy[k*4+0] = yv.x; yy[k*4+1] = yv.y; yy[k*4+2] = yv.z; yy[k*4+3] = yv.w;
        mm[k*4+0] = mv.x; mm[k*4+1] = mv.y; mm[k*4+2] = mv.z; mm[k*4+3] = mv.w;
    }

    // ---- compute phase ----
    float acc = 0.0f;   // accumulates w[y] * logp_y * mask (positive-sign form)
    #pragma unroll
    for (int j = 0; j < PPT; ++j) {
        const float v0 = a0[j], v1 = a1[j], v2 = a2[j];
        const float m   = fmaxf(fmaxf(v0, v1), v2);
        const float t   = __expf(v0 - m) + __expf(v1 - m) + __expf(v2 - m);
        const float lse = m + __logf(t);
        const int   c   = yy[j];
        const float ay  = (c == 0) ? v0 : ((c == 1) ? v1 : v2);
        const float wy  = (c == 0) ? w0 : ((c == 1) ? w1 : w2);
        const float lp  = fmaxf(ay - lse, LOGMIN);
        acc = fmaf(wy * lp, mm[j], acc);
    }

    // ---- wave (64-lane) reduction ----
    #pragma unroll
    for (int off = 32; off > 0; off >>= 1)
        acc += __shfl_down(acc, off, 64);

    __shared__ float wsum[BLOCK / 64];
    const int lane = threadIdx.x & 63;
    const int wid  = threadIdx.x >> 6;
    if (lane == 0) wsum[wid] = acc;
    __syncthreads();

    if (threadIdx.x == 0) {
        const float sres = wsum[0] + wsum[1] + wsum[2] + wsum[3];
        atomicAdd(out, sres * (-INV_DENOM));   // ce = -w*lp*mask, then / denom
    }
}

extern "C" void kernel_launch(void* const* d_in, const int* in_sizes, int n_in,
                              void* d_out, int out_size, void* d_ws, size_t ws_size,
                              hipStream_t stream) {
    const float* x      = (const float*)d_in[0];
    const int*   y      = (const int*)d_in[1];
    const float* weight = (const float*)d_in[2];
    const float* mask   = (const float*)d_in[3];
    float* out = (float*)d_out;

    zero_out_kernel<<<1, 64, 0, stream>>>(out);
    ce_fused_kernel<<<GRID, BLOCK, 0, stream>>>(x, y, weight, mask, out);
}

// Round 3
// 33.476 us; speedup vs baseline: 1.5637x; 1.5637x over previous
//
#include <hip/hip_runtime.h>
#include <hip/hip_bf16.h>

// Problem constants (fixed by the reference file)
constexpr int B_   = 8;
constexpr int C_   = 3;
constexpr int HW_  = 1024 * 1024;         // H*W = 2^20
constexpr int NPIX = B_ * HW_;            // 8,388,608 pixels = 2^23
constexpr int NV   = NPIX / 4;            // float4 groups = 2^21
constexpr int HWV  = HW_ / 4;             // 262144 = 2^18 vec groups per image
constexpr int BLOCK = 256;
constexpr int GRID  = 2048;               // 8 blocks/CU * 256 CUs, all co-resident

// ln(1e-8)
#define LOGMIN (-18.420680743952367f)
// 1/(B*H*W) = 2^-23 (exact in fp32)
#define INV_DENOM (1.1920928955078125e-07f)

__global__ __launch_bounds__(BLOCK) void ce_partial_kernel(
    const float* __restrict__ x,        // [B][C][H][W]
    const int*   __restrict__ y,        // [B][H][W]
    const float* __restrict__ weight,   // [C]
    const float* __restrict__ mask,     // [B][H][W]
    float* __restrict__ partials)       // [GRID]
{
    const float w0 = weight[0];
    const float w1 = weight[1];
    const float w2 = weight[2];

    float acc = 0.0f;   // accumulates w[y] * logp_y * mask (positive-sign form)

    const int tid    = blockIdx.x * BLOCK + threadIdx.x;
    const int stride = GRID * BLOCK;

    for (int pv = tid; pv < NV; pv += stride) {
        const int b  = pv >> 18;            // pv / HWV
        const int sv = pv & (HWV - 1);      // pv % HWV
        const size_t base = (size_t)b * (size_t)(C_ * HW_) + (size_t)sv * 4;

        const float4 xa = *reinterpret_cast<const float4*>(x + base);
        const float4 xb = *reinterpret_cast<const float4*>(x + base + HW_);
        const float4 xc = *reinterpret_cast<const float4*>(x + base + 2 * (size_t)HW_);
        const int4   yv = *reinterpret_cast<const int4*>(y + (size_t)pv * 4);
        const float4 mv = *reinterpret_cast<const float4*>(mask + (size_t)pv * 4);

        const float a0[4] = {xa.x, xa.y, xa.z, xa.w};
        const float a1[4] = {xb.x, xb.y, xb.z, xb.w};
        const float a2[4] = {xc.x, xc.y, xc.z, xc.w};
        const int   yy[4] = {yv.x, yv.y, yv.z, yv.w};
        const float mm[4] = {mv.x, mv.y, mv.z, mv.w};

        #pragma unroll
        for (int j = 0; j < 4; ++j) {
            const float v0 = a0[j], v1 = a1[j], v2 = a2[j];
            const float m   = fmaxf(fmaxf(v0, v1), v2);
            const float t   = __expf(v0 - m) + __expf(v1 - m) + __expf(v2 - m);
            const float lse = m + __logf(t);
            const int   c   = yy[j];
            const float ay  = (c == 0) ? v0 : ((c == 1) ? v1 : v2);
            const float wy  = (c == 0) ? w0 : ((c == 1) ? w1 : w2);
            const float lp  = fmaxf(ay - lse, LOGMIN);
            acc = fmaf(wy * lp, mm[j], acc);
        }
    }

    // wave (64-lane) reduction
    #pragma unroll
    for (int off = 32; off > 0; off >>= 1)
        acc += __shfl_down(acc, off, 64);

    __shared__ float wsum[BLOCK / 64];
    const int lane = threadIdx.x & 63;
    const int wid  = threadIdx.x >> 6;
    if (lane == 0) wsum[wid] = acc;
    __syncthreads();

    if (threadIdx.x == 0)
        partials[blockIdx.x] = wsum[0] + wsum[1] + wsum[2] + wsum[3];
}

__global__ __launch_bounds__(256) void reduce_kernel(
    const float* __restrict__ partials, float* __restrict__ out)
{
    float s = 0.0f;
    #pragma unroll
    for (int i = threadIdx.x; i < GRID; i += 256)
        s += partials[i];

    #pragma unroll
    for (int off = 32; off > 0; off >>= 1)
        s += __shfl_down(s, off, 64);

    __shared__ float wsum[4];
    const int lane = threadIdx.x & 63;
    const int wid  = threadIdx.x >> 6;
    if (lane == 0) wsum[wid] = s;
    __syncthreads();

    if (threadIdx.x == 0) {
        const float total = wsum[0] + wsum[1] + wsum[2] + wsum[3];
        out[0] = total * (-INV_DENOM);   // ce = -w*lp*mask, then / denom
    }
}

extern "C" void kernel_launch(void* const* d_in, const int* in_sizes, int n_in,
                              void* d_out, int out_size, void* d_ws, size_t ws_size,
                              hipStream_t stream) {
    const float* x      = (const float*)d_in[0];
    const int*   y      = (const int*)d_in[1];
    const float* weight = (const float*)d_in[2];
    const float* mask   = (const float*)d_in[3];
    float* out      = (float*)d_out;
    float* partials = (float*)d_ws;     // GRID floats = 8 KB << ws_size

    ce_partial_kernel<<<GRID, BLOCK, 0, stream>>>(x, y, weight, mask, partials);
    reduce_kernel<<<1, 256, 0, stream>>>(partials, out);
}